// Round 3
// baseline (211.028 us; speedup 1.0000x reference)
//
#include <hip/hip_runtime.h>
#include <math.h>

#define HW 65536
#define DD 160
#define NB 2
#define DCH 40
#define NSL (DCH + 6)   // 46 slices per chunk incl. halo
#define NCH 4           // D-chunks per batch item

#define SSIM_C1 1e-4f
#define SSIM_C2 9e-4f

struct Gw { float g[7]; };

// Fused SSIM3D: per block = one 32x32 (h,w) tile marching over a 40-slice D-chunk.
// Per slice: stage inputs (prefetched), separable W->H conv of 5 fields,
// insert into 7-deep register ring, D-conv + SSIM when ring full.
// 512 blocks -> 2 blocks/CU so barrier drains overlap across blocks.
__global__ __launch_bounds__(512) void k_fused(
    const float* __restrict__ img1, const float* __restrict__ img2,
    Gw gw, float* __restrict__ partials)
{
    __shared__ float sx[38][40];   // pitch 40 floats = 160B, 16B-aligned rows
    __shared__ float sy[38][40];
    __shared__ float b1[5][38][33];
    __shared__ float red[512];

    const int tid = threadIdx.x;
    const int n  = blockIdx.z >> 2;
    const int o0 = (blockIdx.z & 3) * DCH;
    const int h0 = blockIdx.y * 32;
    const int w0 = blockIdx.x * 32;
    const float* i1 = img1 + (size_t)n * DD * HW;
    const float* i2 = img2 + (size_t)n * DD * HW;

    // staging per-thread constants (3 rounds x 512 threads cover 38x38=1444 px)
    int goff[3], loff[3];
    bool ok[3], wr[3];
#pragma unroll
    for (int q = 0; q < 3; ++q) {
        int idx = tid + 512 * q;
        int hh = idx / 38;
        int ww = idx - 38 * hh;
        int gh = h0 - 3 + hh;
        int gw2 = w0 - 3 + ww;
        wr[q] = (idx < 1444);
        ok[q] = wr[q] && ((unsigned)gh < 256u) && ((unsigned)gw2 < 256u);
        goff[q] = gh * 256 + gw2;
        loff[q] = hh * 40 + ww;
    }

    const int wcol = tid & 31;
    const int hb = (tid >> 5) * 2;   // 2 output rows per thread

    float ring[2][5][7] = {};
    float lsum = 0.f;

    float* sxf = &sx[0][0];
    float* syf = &sy[0][0];

    // prologue: stage r=0 slice (s = o0-3) if it's a real slice
    {
        int s0 = o0 - 3;
        if (s0 >= 0) {
            const float* p1 = i1 + (size_t)s0 * HW;
            const float* p2 = i2 + (size_t)s0 * HW;
#pragma unroll
            for (int q = 0; q < 3; ++q) {
                float vx = ok[q] ? p1[goff[q]] : 0.f;
                float vy = ok[q] ? p2[goff[q]] : 0.f;
                if (wr[q]) { sxf[loff[q]] = vx; syf[loff[q]] = vy; }
            }
        }
        __syncthreads();
    }

    for (int t = 0; t < 7; ++t) {
#pragma unroll
        for (int p = 0; p < 7; ++p) {
            const int r = 7 * t + p;
            if (r < NSL) {
                const int s = o0 - 3 + r;
                const bool curv = (s >= 0 && s < DD);
                const int sn = s + 1;
                const bool nxtv = (r + 1 < NSL) && (sn >= 0) && (sn < DD);

                // 1) issue next slice's global loads early (latency hides under W-pass)
                float pfx[3], pfy[3];
                if (nxtv) {
                    const float* p1 = i1 + (size_t)sn * HW;
                    const float* p2 = i2 + (size_t)sn * HW;
#pragma unroll
                    for (int q = 0; q < 3; ++q) {
                        pfx[q] = ok[q] ? p1[goff[q]] : 0.f;
                        pfy[q] = ok[q] ? p2[goff[q]] : 0.f;
                    }
                }

                // 2) W-pass: 38 rows x 8 runs-of-4 = 304 tasks
                if (curv && tid < 304) {
                    const int hh = tid >> 3;
                    const int wb = (tid & 7) * 4;
                    float xv[10], yv[10], pxx[10], pyy[10], pxy[10];
#pragma unroll
                    for (int i = 0; i < 10; ++i) { xv[i] = sx[hh][wb + i]; yv[i] = sy[hh][wb + i]; }
#pragma unroll
                    for (int i = 0; i < 10; ++i) {
                        pxx[i] = xv[i] * xv[i]; pyy[i] = yv[i] * yv[i]; pxy[i] = xv[i] * yv[i];
                    }
                    float a[4][5] = {};
#pragma unroll
                    for (int k = 0; k < 7; ++k) {
                        const float gk = gw.g[k];
#pragma unroll
                        for (int o = 0; o < 4; ++o) {
                            const int i = o + k;
                            a[o][0] += gk * xv[i];
                            a[o][1] += gk * yv[i];
                            a[o][2] += gk * pxx[i];
                            a[o][3] += gk * pyy[i];
                            a[o][4] += gk * pxy[i];
                        }
                    }
#pragma unroll
                    for (int f = 0; f < 5; ++f)
#pragma unroll
                        for (int o = 0; o < 4; ++o) b1[f][hh][wb + o] = a[o][f];
                }
                __syncthreads();

                // 3) write prefetched next slice into sx/sy (reads of slice s are done)
                if (nxtv) {
#pragma unroll
                    for (int q = 0; q < 3; ++q)
                        if (wr[q]) { sxf[loff[q]] = pfx[q]; syf[loff[q]] = pfy[q]; }
                }

                // 4) H-pass -> ring insert at phase p
                if (curv) {
#pragma unroll
                    for (int f = 0; f < 5; ++f) {
                        float v[8];
#pragma unroll
                        for (int i = 0; i < 8; ++i) v[i] = b1[f][hb + i][wcol];
#pragma unroll
                        for (int o = 0; o < 2; ++o) {
                            float acc = 0.f;
#pragma unroll
                            for (int k = 0; k < 7; ++k) acc += gw.g[k] * v[o + k];
                            ring[o][f][p] = acc;
                        }
                    }
                } else {
#pragma unroll
                    for (int o = 0; o < 2; ++o)
#pragma unroll
                        for (int f = 0; f < 5; ++f) ring[o][f][p] = 0.f;
                }

                // 5) D-conv + SSIM for output slice r-6
                if (r >= 6) {
#pragma unroll
                    for (int o = 0; o < 2; ++o) {
                        float c0 = 0.f, c1 = 0.f, c2 = 0.f, c3 = 0.f, c4 = 0.f;
#pragma unroll
                        for (int k = 0; k < 7; ++k) {
                            const float gk = gw.g[k];
                            const int pp = (p + 1 + k) % 7;
                            c0 += gk * ring[o][0][pp];
                            c1 += gk * ring[o][1][pp];
                            c2 += gk * ring[o][2][pp];
                            c3 += gk * ring[o][3][pp];
                            c4 += gk * ring[o][4][pp];
                        }
                        const float mu1 = c0, mu2 = c1;
                        const float mu1s = mu1 * mu1, mu2s = mu2 * mu2, m12 = mu1 * mu2;
                        const float s1 = c2 - mu1s, s2 = c3 - mu2s, s12 = c4 - m12;
                        const float num = (2.f * m12 + SSIM_C1) * (2.f * s12 + SSIM_C2);
                        const float den = (mu1s + mu2s + SSIM_C1) * (s1 + s2 + SSIM_C2);
                        lsum += num / den;
                    }
                }
                __syncthreads();
            }
        }
    }

    // deterministic block reduction
    red[tid] = lsum;
    __syncthreads();
    for (int off = 256; off > 0; off >>= 1) {
        if (tid < off) red[tid] += red[tid + off];
        __syncthreads();
    }
    if (tid == 0)
        partials[(blockIdx.z * gridDim.y + blockIdx.y) * gridDim.x + blockIdx.x] = red[0];
}

__global__ __launch_bounds__(256) void k_final(
    const float* __restrict__ partials, int n, float scale, float* __restrict__ out)
{
    __shared__ float red[256];
    float s = 0.f;
    for (int i = threadIdx.x; i < n; i += 256) s += partials[i];
    red[threadIdx.x] = s;
    __syncthreads();
    for (int off = 128; off > 0; off >>= 1) {
        if (threadIdx.x < off) red[threadIdx.x] += red[threadIdx.x + off];
        __syncthreads();
    }
    if (threadIdx.x == 0) out[0] = red[0] * scale;
}

extern "C" void kernel_launch(void* const* d_in, const int* in_sizes, int n_in,
                              void* d_out, int out_size, void* d_ws, size_t ws_size,
                              hipStream_t stream)
{
    const float* img1 = (const float*)d_in[0];
    const float* img2 = (const float*)d_in[1];
    float* out = (float*)d_out;
    float* partials = (float*)d_ws;

    Gw gw;
    {
        double gs[7], sum = 0.0;
        for (int i = 0; i < 7; ++i) { double x = i - 3; gs[i] = exp(-x * x / 4.5); sum += gs[i]; }
        for (int i = 0; i < 7; ++i) gw.g[i] = (float)(gs[i] / sum);
    }

    dim3 grid(8, 8, NB * NCH);   // 512 blocks -> 2 per CU
    k_fused<<<grid, dim3(512), 0, stream>>>(img1, img2, gw, partials);
    k_final<<<dim3(1), dim3(256), 0, stream>>>(
        partials, 8 * 8 * NB * NCH, (float)(1.0 / 20971520.0), out);
}

// Round 4
// 207.475 us; speedup vs baseline: 1.0171x; 1.0171x over previous
//
#include <hip/hip_runtime.h>
#include <math.h>

#define HW 65536
#define DD 160
#define NB 2
#define DCH 80
#define NSL (DCH + 6)   // 86 slices per chunk incl. halo
#define NCH 2

#define SSIM_C1 1e-4f
#define SSIM_C2 9e-4f

struct Gw { float g[7]; };

// Fused SSIM3D, v3: no input staging (W-threads read own windows from global/L1,
// prefetched one slice ahead into registers); transposed double-buffered conv_w
// intermediate in LDS (b64-mergeable H reads, conflict-free pitch 42);
// ONE barrier per slice.
__global__ __launch_bounds__(512, 2) void k_fused(
    const float* __restrict__ img1, const float* __restrict__ img2,
    Gw gw, float* __restrict__ partials)
{
    __shared__ float b1t[2][5][32][42];   // [buf][field][w][h padded]
    __shared__ float red[512];

    const int tid = threadIdx.x;
    const int nb = blockIdx.z >> 1;
    const int o0 = (blockIdx.z & 1) * DCH;
    const int h0 = blockIdx.y * 32;
    const int w0 = blockIdx.x * 32;
    const float* i1 = img1 + (size_t)nb * DD * HW;
    const float* i2 = img2 + (size_t)nb * DD * HW;

    // ---- W-thread geometry (tid < 304): row hh, 4 outputs at w0+wb.. ----
    const int hh = tid >> 3;
    const int wb = (tid & 7) * 4;
    const int gh = h0 - 3 + hh;
    const int gwb = w0 - 3 + wb;
    const bool wth = (tid < 304);
    const bool ghv = wth && ((unsigned)gh < 256u);
    const int ghc = gh < 0 ? 0 : (gh > 255 ? 255 : gh);
    int coff[10];
    float msk[10];
#pragma unroll
    for (int i = 0; i < 10; ++i) {
        int gwi = gwb + i;
        int gc = gwi < 0 ? 0 : (gwi > 255 ? 255 : gwi);
        coff[i] = ghc * 256 + gc;                    // always in-bounds address
        msk[i] = (ghv && gwi == gc) ? 1.f : 0.f;     // zero-pad mask
    }

    // ---- H/D-thread geometry: all 512 threads, 2 output rows each ----
    const int wcol = tid & 31;
    const int hb = (tid >> 5) * 2;

    float ring[2][5][7] = {};
    float lsum = 0.f;
    float cx[10], cy[10];

    // prologue: load slice r=0 (s = o0-3) into cx/cy
    {
        const int s0 = o0 - 3;
        if (s0 >= 0 && wth) {
            const float* p1 = i1 + (size_t)s0 * HW;
            const float* p2 = i2 + (size_t)s0 * HW;
#pragma unroll
            for (int i = 0; i < 10; ++i) {
                cx[i] = p1[coff[i]] * msk[i];
                cy[i] = p2[coff[i]] * msk[i];
            }
        }
    }

    for (int t = 0; t < 13; ++t) {
#pragma unroll
        for (int p = 0; p < 7; ++p) {
            const int r = 7 * t + p;
            if (r <= NSL) {
                const int scur = o0 - 3 + r;
                const bool wv = (r < NSL) && (scur >= 0) && (scur < DD);
                const int snx = scur + 1;
                const bool pfv = (r + 1 < NSL) && (snx >= 0) && (snx < DD);

                // 1) issue next slice's global loads (consumed at iteration end)
                float pfx[10], pfy[10];
                if (pfv && wth) {
                    const float* p1 = i1 + (size_t)snx * HW;
                    const float* p2 = i2 + (size_t)snx * HW;
#pragma unroll
                    for (int i = 0; i < 10; ++i) pfx[i] = p1[coff[i]];
#pragma unroll
                    for (int i = 0; i < 10; ++i) pfy[i] = p2[coff[i]];
                }

                // 2) W-pass from registers -> b1t[r&1]
                if (wv && wth) {
                    float a[4][5] = {};
#pragma unroll
                    for (int i = 0; i < 10; ++i) {
                        const float xx = cx[i] * cx[i];
                        const float yy = cy[i] * cy[i];
                        const float xy = cx[i] * cy[i];
#pragma unroll
                        for (int o = 0; o < 4; ++o) {
                            const int k = i - o;
                            if (k >= 0 && k < 7) {
                                const float gk = gw.g[k];
                                a[o][0] += gk * cx[i];
                                a[o][1] += gk * cy[i];
                                a[o][2] += gk * xx;
                                a[o][3] += gk * yy;
                                a[o][4] += gk * xy;
                            }
                        }
                    }
                    float* bb = &b1t[r & 1][0][0][0];
#pragma unroll
                    for (int f = 0; f < 5; ++f)
#pragma unroll
                        for (int o = 0; o < 4; ++o)
                            bb[f * (32 * 42) + (wb + o) * 42 + hh] = a[o][f];
                }

                // 3) H-pass + D-ring + SSIM for slice rp = r-1 (reads other buffer)
                if (r >= 1) {
                    const int rp = r - 1;
                    const int sp = o0 - 3 + rp;
                    const int pi = (p + 6) % 7;   // == rp % 7, compile-time
                    if (sp >= 0 && sp < DD) {
                        const float* br = &b1t[rp & 1][0][0][0];
#pragma unroll
                        for (int f = 0; f < 5; ++f) {
                            float v[8];
#pragma unroll
                            for (int i = 0; i < 8; ++i)
                                v[i] = br[f * (32 * 42) + wcol * 42 + hb + i];
#pragma unroll
                            for (int o = 0; o < 2; ++o) {
                                float acc = 0.f;
#pragma unroll
                                for (int k = 0; k < 7; ++k) acc += gw.g[k] * v[o + k];
                                ring[o][f][pi] = acc;
                            }
                        }
                    } else {
#pragma unroll
                        for (int o = 0; o < 2; ++o)
#pragma unroll
                            for (int f = 0; f < 5; ++f) ring[o][f][pi] = 0.f;
                    }
                    if (r >= 7) {
#pragma unroll
                        for (int o = 0; o < 2; ++o) {
                            float c0 = 0.f, c1 = 0.f, c2 = 0.f, c3 = 0.f, c4 = 0.f;
#pragma unroll
                            for (int k = 0; k < 7; ++k) {
                                const float gk = gw.g[k];
                                const int pp = (pi + 1 + k) % 7;
                                c0 += gk * ring[o][0][pp];
                                c1 += gk * ring[o][1][pp];
                                c2 += gk * ring[o][2][pp];
                                c3 += gk * ring[o][3][pp];
                                c4 += gk * ring[o][4][pp];
                            }
                            const float mu1 = c0, mu2 = c1;
                            const float mu1s = mu1 * mu1, mu2s = mu2 * mu2, m12 = mu1 * mu2;
                            const float s1 = c2 - mu1s, s2 = c3 - mu2s, s12 = c4 - m12;
                            const float num = (2.f * m12 + SSIM_C1) * (2.f * s12 + SSIM_C2);
                            const float den = (mu1s + mu2s + SSIM_C1) * (s1 + s2 + SSIM_C2);
                            lsum += num / den;
                        }
                    }
                }

                // 4) register handoff: next slice's data becomes current
                if (pfv && wth) {
#pragma unroll
                    for (int i = 0; i < 10; ++i) {
                        cx[i] = pfx[i] * msk[i];
                        cy[i] = pfy[i] * msk[i];
                    }
                }
                __syncthreads();
            }
        }
    }

    // deterministic block reduction
    red[tid] = lsum;
    __syncthreads();
    for (int off = 256; off > 0; off >>= 1) {
        if (tid < off) red[tid] += red[tid + off];
        __syncthreads();
    }
    if (tid == 0)
        partials[(blockIdx.z * gridDim.y + blockIdx.y) * gridDim.x + blockIdx.x] = red[0];
}

__global__ __launch_bounds__(256) void k_final(
    const float* __restrict__ partials, int n, float scale, float* __restrict__ out)
{
    __shared__ float red[256];
    float s = 0.f;
    for (int i = threadIdx.x; i < n; i += 256) s += partials[i];
    red[threadIdx.x] = s;
    __syncthreads();
    for (int off = 128; off > 0; off >>= 1) {
        if (threadIdx.x < off) red[threadIdx.x] += red[threadIdx.x + off];
        __syncthreads();
    }
    if (threadIdx.x == 0) out[0] = red[0] * scale;
}

extern "C" void kernel_launch(void* const* d_in, const int* in_sizes, int n_in,
                              void* d_out, int out_size, void* d_ws, size_t ws_size,
                              hipStream_t stream)
{
    const float* img1 = (const float*)d_in[0];
    const float* img2 = (const float*)d_in[1];
    float* out = (float*)d_out;
    float* partials = (float*)d_ws;

    Gw gw;
    {
        double gs[7], sum = 0.0;
        for (int i = 0; i < 7; ++i) { double x = i - 3; gs[i] = exp(-x * x / 4.5); sum += gs[i]; }
        for (int i = 0; i < 7; ++i) gw.g[i] = (float)(gs[i] / sum);
    }

    dim3 grid(8, 8, NB * NCH);   // 256 blocks
    k_fused<<<grid, dim3(512), 0, stream>>>(img1, img2, gw, partials);
    k_final<<<dim3(1), dim3(256), 0, stream>>>(
        partials, 8 * 8 * NB * NCH, (float)(1.0 / 20971520.0), out);
}